// Round 12
// baseline (113.382 us; speedup 1.0000x reference)
//
#include <hip/hip_runtime.h>

// Self-attention (SAGAN-style): B=8, C=64, H=W=64 -> N=4096, E=C/8=8.
// Round 12: widen the attn inner loop to 64 keys/group (2 panels: 6 loads,
// 12 MFMA, 32 independent exps per group) -- doubles the schedulable ILP
// window between dependent MFMA->exp->pack->MFMA chains and halves loop
// control; depth-2 group prefetch (~128 keys ahead). Also hoist the
// epilogue's 8 residual x-loads to kernel start (they depend on nothing;
// kills the cold ~900cyc HBM stall after the combine barrier).
// Kept from r6-r11 (all verified): 2 q-tiles/wave (32q/block, 1024 blocks),
// panelized V [b][128][16][32] with ones-row 8 (l = sum(p) via GEMM2 on the
// MFMA pipe), in-register P via permuted key map, quad-independent unmasked
// K loads (x qf zero rows), V row-clamp lmv=min(lm,8), raw v_exp, v_perm
// pack, fused Wo/residual epilogue, LDS-free 3-pass qkv.
// Non-attn ~84us = harness 0xAA re-poison fills (2x268MB at ~79% HBM peak)
// -- fixed; attn is the only lever.

#define BB   8
#define CC   64
#define NPIX 4096
#define EE   8
#define BN   (BB*NPIX)        // 32768
#define YSZ  (BB*CC*NPIX)     // 2097152
#define LOG2E 1.4426950408889634f

typedef __attribute__((ext_vector_type(8))) short bf16x8;
typedef __attribute__((ext_vector_type(4))) float f32x4;

__device__ __forceinline__ unsigned short f2bf_rne(float x) {
    unsigned u = __float_as_uint(x);
    u += 0x7FFFu + ((u >> 16) & 1u);
    return (unsigned short)(u >> 16);
}
// dst = [hi16(a), hi16(b)] in one v_perm_b32 (truncation; bias cancels in
// the softmax normalize since l sums the same truncated p via the ones-row).
__device__ __forceinline__ unsigned pack_bf_trunc(float a, float b) {
    return __builtin_amdgcn_perm(__float_as_uint(b), __float_as_uint(a),
                                 0x07060302u);
}

// ---- K1: QKV projection; V written in panel layout (unchanged from r9) ----
__global__ __launch_bounds__(256) void qkv_kernel(
    const float* __restrict__ x,
    const float* __restrict__ Wk, const float* __restrict__ bk,
    const float* __restrict__ Wq, const float* __restrict__ bq,
    const float* __restrict__ Wv, const float* __restrict__ bv,
    unsigned short* __restrict__ QT, unsigned short* __restrict__ KT,
    unsigned short* __restrict__ VT)
{
    const int proj = blockIdx.y;  // 0=Q, 1=K, 2=V
    const float* W    = (proj == 0) ? Wq : (proj == 1) ? Wk : Wv;
    const float* bias = (proj == 0) ? bq : (proj == 1) ? bk : bv;

    const int bm = blockIdx.x*256 + threadIdx.x;
    const int b  = bm >> 12;
    const int n  = bm & (NPIX-1);
    const float* xb = x + (size_t)b*CC*NPIX + n;

    float xv[CC];
    #pragma unroll
    for (int c = 0; c < CC; ++c) xv[c] = xb[(size_t)c*NPIX];

    float f[EE];
    #pragma unroll
    for (int e = 0; e < EE; ++e) {
        float acc = bias[e];
        #pragma unroll
        for (int c = 0; c < CC; ++c) acc = fmaf(W[e*CC+c], xv[c], acc);
        f[e] = acc;
    }

    if (proj == 0) {
        union { unsigned short s[8]; uint4 v; } t;
        #pragma unroll
        for (int e = 0; e < EE; ++e) t.s[e] = f2bf_rne(f[e] * LOG2E);
        *(uint4*)(QT + (size_t)bm*EE) = t.v;
    } else if (proj == 1) {
        union { unsigned short s[8]; uint4 v; } t;
        #pragma unroll
        for (int e = 0; e < EE; ++e) t.s[e] = f2bf_rne(f[e]);
        *(uint4*)(KT + (size_t)bm*EE) = t.v;
    } else {
        // panel p = n>>5; within-row short offset for key c = n&31:
        // quad q(c) block of 8: [0..3]=keys 4q..4q+3, [4..7]=keys 16+4q..+3
        const int p   = n >> 5;
        const int c   = n & 31;
        const int off = ((c & 15) >> 2)*8 + ((c >> 4) << 2) + (c & 3);
        unsigned short* vp = VT + ((size_t)(b*128 + p)*16)*32 + off;
        #pragma unroll
        for (int e = 0; e < EE; ++e) vp[e*32] = f2bf_rne(f[e]);
        vp[8*32] = 0x3F80;                         // ones row -> l via GEMM2
    }
}

// ---- K2: flash attention, 2 q-tiles/wave, 64-key groups + fused epilogue --
// Block = 32 queries; 4 waves split the 4096 keys x4. Grid = 8*128 = 1024.
__global__ __launch_bounds__(256, 4) void attn_fused(
    const unsigned short* __restrict__ QT, const unsigned short* __restrict__ KT,
    const unsigned short* __restrict__ VT,
    const float* __restrict__ x, const float* __restrict__ Wo,
    const float* __restrict__ bo, const float* __restrict__ gamma,
    float* __restrict__ out)
{
    __shared__ float OB[3*2*256];  // waves 1..3 x {A,B} x 64 lanes x f32x4
    __shared__ float VL[32*12];    // normalized v per pixel
    __shared__ float Wos[CC*9];    // stride 9: conflict-free epilogue reads
    __shared__ float bos[CC];

    const int tid  = threadIdx.x;
    const int wave = tid >> 6, lane = tid & 63;
    const int quad = lane >> 4, lm = lane & 15;
    const int b  = blockIdx.x >> 7;
    const int m0 = (blockIdx.x & 127) * 32;

    for (int i = tid; i < CC*EE; i += 256) Wos[(i>>3)*9 + (i&7)] = Wo[i];
    if (tid < CC) bos[tid] = bo[tid];

    // Hoisted epilogue x-loads: independent of the main loop; complete long
    // before the combine barrier (kills the end-of-kernel HBM stall).
    const int   px = tid & 31;
    const int   cg = tid >> 5;                     // 0..7 -> 8 channels each
    const size_t base = (size_t)b*CC*NPIX + (m0 + px);
    float xpre[8];
    #pragma unroll
    for (int i = 0; i < 8; ++i) xpre[i] = x[base + (size_t)(cg*8 + i)*NPIX];

    // B1 operands: only quad0 lanes carry real q rows; others stay zero.
    bf16x8 qfA = {0,0,0,0,0,0,0,0}, qfB = {0,0,0,0,0,0,0,0};
    if (quad == 0) {
        qfA = *(const bf16x8*)(QT + (size_t)(b*NPIX + m0 + lm)*EE);
        qfB = *(const bf16x8*)(QT + (size_t)(b*NPIX + m0 + 16 + lm)*EE);
    }

    f32x4 oaccA = {0.f,0.f,0.f,0.f}, oaccB = {0.f,0.f,0.f,0.f};
    const f32x4 zc = {0.f,0.f,0.f,0.f};

    const unsigned short* Kb = KT + (size_t)b*NPIX*EE;
    const int n_start = wave*1024;                 // split-K: 1024 keys/wave
    // K address is quad-independent: all quads hit the same 256B segment;
    // quads 1..3 hold real K x qf zero rows = 0 contribution.
    const unsigned short* kl = Kb + (size_t)(n_start + lm)*EE;
    // V panel: row clamp (rows 9..15 -> 8; same lines, C rows 9..15 discarded)
    const int lmv = (lm < 9) ? lm : 8;
    const unsigned short* vl = VT + ((size_t)(b*128 + (n_start >> 5))*16 + lmv)*32
                                  + quad*8;

    // 2-deep pipeline of 64-key GROUPS (2 panels each): A = group g, B = g+1.
    bf16x8 kA0 = *(const bf16x8*)(kl);
    bf16x8 kA1 = *(const bf16x8*)(kl + 128);
    bf16x8 kA2 = *(const bf16x8*)(kl + 256);
    bf16x8 kA3 = *(const bf16x8*)(kl + 384);
    bf16x8 vA0 = *(const bf16x8*)(vl);
    bf16x8 vA1 = *(const bf16x8*)(vl + 512);
    bf16x8 kB0 = *(const bf16x8*)(kl + 512);
    bf16x8 kB1 = *(const bf16x8*)(kl + 640);
    bf16x8 kB2 = *(const bf16x8*)(kl + 768);
    bf16x8 kB3 = *(const bf16x8*)(kl + 896);
    bf16x8 vB0 = *(const bf16x8*)(vl + 1024);
    bf16x8 vB1 = *(const bf16x8*)(vl + 1536);
    kl += 1024; vl += 2048;                        // -> group g+2

    #pragma unroll 2
    for (int g = 0; g < 16; ++g) {
        bf16x8 k0 = kA0, k1 = kA1, k2 = kA2, k3 = kA3, v0 = vA0, v1 = vA1;
        kA0 = kB0; kA1 = kB1; kA2 = kB2; kA3 = kB3; vA0 = vB0; vA1 = vB1;
        if (g < 14) {                              // prefetch group g+2
            kB0 = *(const bf16x8*)(kl);
            kB1 = *(const bf16x8*)(kl + 128);
            kB2 = *(const bf16x8*)(kl + 256);
            kB3 = *(const bf16x8*)(kl + 384);
            vB0 = *(const bf16x8*)(vl);
            vB1 = *(const bf16x8*)(vl + 512);
            kl += 512; vl += 1024;
        }

        #pragma unroll
        for (int h = 0; h < 2; ++h) {              // two 32-key chunks
            bf16x8 kf0 = h ? k2 : k0, kf1 = h ? k3 : k1, vf = h ? v1 : v0;

            // S: C-layout lane (quad,lm) reg r = S[key][query];
            // s0: key = 4*quad + r; s1: key = 16 + 4*quad + r.
            f32x4 s0a = __builtin_amdgcn_mfma_f32_16x16x32_bf16(kf0, qfA, zc, 0, 0, 0);
            f32x4 s1a = __builtin_amdgcn_mfma_f32_16x16x32_bf16(kf1, qfA, zc, 0, 0, 0);
            f32x4 s0b = __builtin_amdgcn_mfma_f32_16x16x32_bf16(kf0, qfB, zc, 0, 0, 0);
            f32x4 s1b = __builtin_amdgcn_mfma_f32_16x16x32_bf16(kf1, qfB, zc, 0, 0, 0);

            float a0 = __builtin_amdgcn_exp2f(s0a.x), a1 = __builtin_amdgcn_exp2f(s0a.y);
            float a2 = __builtin_amdgcn_exp2f(s0a.z), a3 = __builtin_amdgcn_exp2f(s0a.w);
            float a4 = __builtin_amdgcn_exp2f(s1a.x), a5 = __builtin_amdgcn_exp2f(s1a.y);
            float a6 = __builtin_amdgcn_exp2f(s1a.z), a7 = __builtin_amdgcn_exp2f(s1a.w);
            float b0 = __builtin_amdgcn_exp2f(s0b.x), b1 = __builtin_amdgcn_exp2f(s0b.y);
            float b2 = __builtin_amdgcn_exp2f(s0b.z), b3 = __builtin_amdgcn_exp2f(s0b.w);
            float b4 = __builtin_amdgcn_exp2f(s1b.x), b5 = __builtin_amdgcn_exp2f(s1b.y);
            float b6 = __builtin_amdgcn_exp2f(s1b.z), b7 = __builtin_amdgcn_exp2f(s1b.w);

            // B2 fragment IS the C-layout regs under the permuted key map
            // (slot k=quad*8+j -> key quad*4+j (j<4) / 16+quad*4+(j-4)),
            // matching the V panel row layout. Verified r6-r11.
            union { unsigned u[4]; bf16x8 v; } puA, puB;
            puA.u[0] = pack_bf_trunc(a0, a1); puA.u[1] = pack_bf_trunc(a2, a3);
            puA.u[2] = pack_bf_trunc(a4, a5); puA.u[3] = pack_bf_trunc(a6, a7);
            puB.u[0] = pack_bf_trunc(b0, b1); puB.u[1] = pack_bf_trunc(b2, b3);
            puB.u[2] = pack_bf_trunc(b4, b5); puB.u[3] = pack_bf_trunc(b6, b7);
            oaccA = __builtin_amdgcn_mfma_f32_16x16x32_bf16(vf, puA.v, oaccA, 0, 0, 0);
            oaccB = __builtin_amdgcn_mfma_f32_16x16x32_bf16(vf, puB.v, oaccB, 0, 0, 0);
        }
    }

    // cross-wave combine; l rides along in C-row 8 (quad2 lanes, reg .x)
    if (wave != 0) {
        *(f32x4*)(OB + ((size_t)(wave-1)*2 + 0)*256 + lane*4) = oaccA;
        *(f32x4*)(OB + ((size_t)(wave-1)*2 + 1)*256 + lane*4) = oaccB;
    }
    __syncthreads();
    if (wave == 0) {
        f32x4 oA = oaccA, oB = oaccB;
        #pragma unroll
        for (int w = 0; w < 3; ++w) {
            oA += *(f32x4*)(OB + ((size_t)w*2 + 0)*256 + lane*4);
            oB += *(f32x4*)(OB + ((size_t)w*2 + 1)*256 + lane*4);
        }
        float lA = __shfl(oA.x, 32 + lm);          // row 8 = sum of trunc(p)
        float lB = __shfl(oB.x, 32 + lm);
        float invA = 1.f / lA, invB = 1.f / lB;
        if (quad < 2) {                            // rows e = quad*4+reg in 0..7
            f32x4 sA = { oA.x*invA, oA.y*invA, oA.z*invA, oA.w*invA };
            f32x4 sB = { oB.x*invB, oB.y*invB, oB.z*invB, oB.w*invB };
            *(f32x4*)(VL + lm*12 + quad*4)        = sA;
            *(f32x4*)(VL + (16 + lm)*12 + quad*4) = sB;
        }
    }
    __syncthreads();

    // Fused epilogue: 32 px x 64 ch over 256 threads (8 ch each).
    const float g  = gamma[0];
    float v[EE];
    #pragma unroll
    for (int e = 0; e < EE; ++e) v[e] = VL[px*12 + e];
    #pragma unroll
    for (int i = 0; i < 8; ++i) {
        const int c = cg*8 + i;
        float o = bos[c];
        #pragma unroll
        for (int e = 0; e < EE; ++e) o += Wos[c*9 + e] * v[e];
        out[(size_t)YSZ + base + (size_t)c*NPIX] = o;
        out[base + (size_t)c*NPIX] = g*o + xpre[i];
    }
    if (blockIdx.x == 0 && tid == 0) out[2*(size_t)YSZ] = g;  // gamma passthrough
}

extern "C" void kernel_launch(void* const* d_in, const int* in_sizes, int n_in,
                              void* d_out, int out_size, void* d_ws, size_t ws_size,
                              hipStream_t stream) {
    const float* x     = (const float*)d_in[0];
    const float* Wk    = (const float*)d_in[1];
    const float* bk    = (const float*)d_in[2];
    const float* Wq    = (const float*)d_in[3];
    const float* bq    = (const float*)d_in[4];
    const float* Wv    = (const float*)d_in[5];
    const float* bv    = (const float*)d_in[6];
    const float* Wo    = (const float*)d_in[7];
    const float* bo    = (const float*)d_in[8];
    const float* gamma = (const float*)d_in[9];
    float* out = (float*)d_out;

    // ws: QT(512KB) | KT(512KB) | VT(1MB bf16, panelized [b][128][16][32];
    // row 8 = ones, rows 9..15 poison -> only discarded C rows) = 2MB
    unsigned short* QT = (unsigned short*)d_ws;
    unsigned short* KT = QT + (size_t)BN*EE;
    unsigned short* VT = KT + (size_t)BN*EE;

    qkv_kernel<<<dim3(BN/256, 3), 256, 0, stream>>>(x, Wk, bk, Wq, bq, Wv, bv, QT, KT, VT);
    attn_fused<<<BB*128, 256, 0, stream>>>(QT, KT, VT, x, Wo, bo, gamma, out);
}